// Round 18
// baseline (415.741 us; speedup 1.0000x reference)
//
#include <hip/hip_runtime.h>

#define PS 7
#define NP 10
#define WIN 20
#define STR 4
#define LL 14          // WIN - PS + 1
#define HALF 7
#define HH 160
#define WW 160
#define BCN 32         // B*C
#define NX 36          // positions per axis
#define PPOS 1296      // NX*NX
#define EMBD 128
#define NTASK (BCN * PPOS * NP)   // 414720
#define NEV (PPOS * NP)           // 12960 events per plane
#define CAP 512                   // per-tile event list capacity (8x8 tiles)
#define NTILE 400                 // 20x20 tiles of 8x8 per plane

// ---------------- phase 0: M = Wp@Wb, K[n] = (bp+pos_emb[n])@Wb + bb ---------
__global__ __launch_bounds__(256) void k_mk(const float* __restrict__ Wp,
                                            const float* __restrict__ bp,
                                            const float* __restrict__ pe,
                                            const float* __restrict__ Wb,
                                            const float* __restrict__ bb,
                                            float* __restrict__ M,
                                            float* __restrict__ K) {
    int t = blockIdx.x * 256 + threadIdx.x;
    if (t < 49 * 49) {
        int k = t / 49, d = t % 49;
        float acc = 0.f;
        for (int e = 0; e < EMBD; ++e) acc += Wp[k * EMBD + e] * Wb[e * 49 + d];
        M[t] = acc;
    } else if (t < 49 * 49 + NP * 49) {
        int u = t - 49 * 49;
        int n = u / 49, d = u % 49;
        float acc = bb[d];
        for (int e = 0; e < EMBD; ++e) acc += (bp[e] + pe[n * EMBD + e]) * Wb[e * 49 + d];
        K[u] = acc;
    }
}

// ---------------- phase 1: sim + top-10 + FUSED den (round-16 proven body) ---
// 4 INDEPENDENT waves per block (no LDS, no barriers) — 1-wave blocks capped
// occupancy at the per-CU block limit; packing lifts the cap to the 32-wave
// HW limit. Each wave = one (pos,bc), body identical to round 16.
__global__ __launch_bounds__(256) void k_sim(const float* __restrict__ img,
                                             const float* __restrict__ Mg,
                                             const float* __restrict__ Kg,
                                             unsigned* __restrict__ xy,
                                             float* __restrict__ pd) {
    int tid  = threadIdx.x;
    int wv   = tid >> 6;
    int lane = tid & 63;
    int gt   = blockIdx.x * 4 + wv;
    int pos  = gt % PPOS;
    int bc   = gt / PPOS;
    int ix = pos / NX, iy = pos % NX;
    int x = ix * STR, y = iy * STR;
    int xb0 = max(x - HALF, 0), yb0 = max(y - HALF, 0);
    int jmax = x + 6 - xb0;   // valid j <= jmax
    int imax = y + 6 - yb0;   // <= 13 always
    const float* plane = img + bc * (HH * WW);

    // ref patch 7x7, wave-uniform -> loaded once (scalar-friendly)
    float rf[49];
#pragma unroll
    for (int a = 0; a < PS; ++a)
#pragma unroll
        for (int b = 0; b < PS; ++b)
            rf[a * 7 + b] = plane[(y + a) * WW + (x + b)];

    int B = lane;                      // quad block id, valid < 56
    bool bval = B < 56;
    int gr = B / 14, c = B % 14;       // row-group, col
    int r0 = gr * 4;
    float acc[4] = {0.f, 0.f, 0.f, 0.f};
    const float* wb = plane + yb0 * WW + xb0 + c;
#pragma unroll
    for (int a = 0; a < 10; ++a) {
        int ra = min(r0 + a, 19);      // clamp keeps loads in-window
        const float* rp = wb + ra * WW;
#pragma unroll
        for (int b = 0; b < 7; ++b) {
            float tap = rp[b];
#pragma unroll
            for (int k = 0; k < 4; ++k) {
                int ai = a - k;
                if (ai >= 0 && ai < 7) acc[k] += tap * rf[ai * 7 + b];
            }
        }
    }
    float v[4]; int vidx[4];
#pragma unroll
    for (int k = 0; k < 4; ++k) {
        int rr = r0 + k;
        bool ok = bval && (rr <= imax) && (c <= jmax);  // imax<=13 masks rows 14/15
        v[k] = ok ? acc[k] : -INFINITY;
        vidx[k] = rr * 14 + c;         // monotone in lane per slot
    }

    // M column d cached per lane (rf[] live range ends above -> regs reused)
    int ld = min(lane, 48);
    float Mc[49];
#pragma unroll
    for (int j = 0; j < 49; ++j) Mc[j] = Mg[j * 49 + ld];  // coalesced, L1-hot

    bool act = lane < 49;
    int tbase = (bc * PPOS + pos) * NP;

    for (int n = 0; n < NP; ++n) {
        float bv = fmaxf(fmaxf(v[0], v[1]), fmaxf(v[2], v[3]));
#pragma unroll
        for (int off = 32; off >= 1; off >>= 1)
            bv = fmaxf(bv, __shfl_xor(bv, off));
        unsigned long long ms[4];
        ms[0] = __ballot(v[0] == bv);
        ms[1] = __ballot(v[1] == bv);
        ms[2] = __ballot(v[2] == bv);
        ms[3] = __ballot(v[3] == bv);
        int best = 1 << 30, slotw = 0, lanew = 0;
#pragma unroll
        for (int s = 0; s < 4; ++s) {
            if (ms[s]) {
                int l  = __ffsll(ms[s]) - 1;                       // SGPR
                int id = __builtin_amdgcn_readlane(vidx[s], l);    // SGPR
                if (id < best) { best = id; slotw = s; lanew = l; }
            }
        }
        int bi = best;                       // SGPR raster idx (unique)
#pragma unroll
        for (int s = 0; s < 4; ++s)
            if (s == slotw && lane == lanew) v[s] = -INFINITY;

        int oy = bi / 14, ox = bi % 14;      // SALU
        int x_i = oy + xb0;        // source bug kept: col start = row off + xb0
        int y_i = ox + yb0;        // row start = col off + yb0
        int t = tbase + n;
        if (lane == 0) xy[t] = (unsigned)x_i | ((unsigned)y_i << 8);
        const float* src = plane + (yb0 + oy) * WW + (xb0 + ox);   // uniform base
        // den[lane] = K[n][lane] + sum_j patch_j * Mc[j];
        // patch_j = src[(j%7)*WW + j/7]  (transposed patch, uniform -> s_load)
        float den = Kg[n * 49 + ld];
#pragma unroll
        for (int j = 0; j < 49; ++j)
            den = fmaf(src[(j % 7) * WW + (j / 7)], Mc[j], den);
        if (act) pd[(size_t)t * 49 + lane] = den;
    }
}

// ---------------- phase 3: build (LDS u32 list) + replay (round-14 proven) ---
__global__ __launch_bounds__(256) void k_apply(const float* __restrict__ img,
                                               const unsigned* __restrict__ xy,
                                               const float* __restrict__ pd,
                                               float* __restrict__ out) {
    __shared__ unsigned lsts[4][CAP];
    int tid  = threadIdx.x;
    int wv   = tid >> 6;
    int lane = tid & 63;
    int gt   = blockIdx.x * 4 + wv;          // global tile id
    int bc   = gt / NTILE;
    int tile = gt % NTILE;
    int tx0 = (tile % 20) * 8, ty0 = (tile / 20) * 8;
    int tx1 = tx0 + 7, ty1 = ty0 + 7;
    const unsigned* xs = xy + bc * NEV;
    unsigned* lst = lsts[wv];

    // ---- build: interval-restricted scan ----
    int a0 = (tx0 <= 19) ? 0 : ((tx0 - 9) >> 2), a1 = min(35, (tx0 + 14) >> 2);
    int b0 = (ty0 <= 19) ? 0 : ((ty0 - 9) >> 2), b1 = min(35, (ty0 + 14) >> 2);
    if (a0 > b0) { int t0 = a0; a0 = b0; b0 = t0; int t1 = a1; a1 = b1; b1 = t1; }
    int lo0 = a0, lo1 = 0, len0, len1;
    if (b0 <= a1 + 1) { len0 = max(a1, b1) - lo0 + 1; len1 = 0; }
    else              { len0 = a1 - a0 + 1; lo1 = b0; len1 = b1 - b0 + 1; }
    int nU = len0 + len1;                    // <= 14
    unsigned m = 65536u / (unsigned)nU + 1u; // exact fastdiv (k < 4681, nU <= 14)
    int npos = nU * nU;

    unsigned cnt = 0;
    for (int base = 0; base < npos; base += 64) {
        int k = base + lane;
        bool valid = k < npos;
        unsigned kk = valid ? (unsigned)k : 0u;
        int ki = (int)((kk * m) >> 16);
        int kj = (int)kk - ki * nU;
        int ixp = (ki < len0) ? (lo0 + ki) : (lo1 + ki - len0);
        int iyp = (kj < len0) ? (lo0 + kj) : (lo1 + kj - len0);
        int pos = ixp * NX + iyp;
        const unsigned* ep = xs + pos * NP;

        unsigned ev[NP];
#pragma unroll
        for (int n = 0; n < NP; ++n) ev[n] = ep[n];

        unsigned rel = 0;
        unsigned pk[NP];
#pragma unroll
        for (int n = 0; n < NP; ++n) {
            unsigned u = ev[n];
            int x_i = (int)(u & 255u);
            int y_i = (int)((u >> 8) & 255u);
            bool ih = (x_i <= tx1) && (x_i + 6 >= tx0) &&
                      (y_i <= ty1) && (y_i + 6 >= ty0);
            bool ch = (x_i <= ty1) && (x_i + 6 >= ty0) &&
                      (y_i <= tx1) && (y_i + 6 >= tx0);
            bool any = valid && (ih || ch);
            rel |= any ? (1u << n) : 0u;
            pk[n] = (unsigned)(pos * NP + n) | ((unsigned)x_i << 14) | ((unsigned)y_i << 22)
                  | (ih ? (1u << 30) : 0u) | (ch ? (1u << 31) : 0u);
        }
        int myc = __popc(rel);
        int scan = myc;
#pragma unroll
        for (int off = 1; off < 64; off <<= 1) {
            int o = __shfl_up(scan, off);
            scan += (lane >= off) ? o : 0;
        }
        int excl  = (int)cnt + scan - myc;
        int total = __shfl(scan, 63);
        int w = excl;
#pragma unroll
        for (int n = 0; n < NP; ++n) {
            if ((rel >> n) & 1u) { if (w < CAP) lst[w] = pk[n]; ++w; }
        }
        cnt += (unsigned)total;
    }
    if (cnt > CAP) cnt = CAP;
    unsigned cntp = (cnt + 7u) & ~7u;
    if (cntp > CAP) cntp = CAP;
    if (lane < (int)(cntp - cnt)) lst[cnt + lane] = 0u;   // zero-pad (no-op)
    int cntN = (int)cntp;

    // ---- apply: batch-of-8, scalarized decode, pure predication ----
    int r  = ty0 + (lane >> 3);
    int cc = tx0 + (lane & 7);
    float im = img[bc * (HH * WW) + r * WW + cc];
    float c  = 1.0f;
    const float* ds = pd + (size_t)bc * ((size_t)NEV * 49);
    int vOff = (r * 7 + cc) * 4;   // per-lane byte offset base 4*(7r+cc)

    for (int i = 0; i < cntN; i += 8) {
        unsigned eu[8];
        float    dv[8];
#pragma unroll
        for (int j = 0; j < 8; ++j)
            eu[j] = (unsigned)__builtin_amdgcn_readfirstlane((int)lst[i + j]);
#pragma unroll
        for (int j = 0; j < 8; ++j) {
            unsigned u = eu[j];                       // SGPR
            int t    = (int)(u & 16383u);             // SALU decode
            int x_i  = (int)((u >> 14) & 255u);
            int y_i  = (int)((u >> 22) & 255u);
            int sOff = (y_i * 7 + x_i) * 4;           // SALU
            const char* dsb = (const char*)(ds + (size_t)t * 49);  // SGPR base
            int boc = min(max(vOff - sOff, 0), 192);  // v_sub + clamp
            dv[j] = *(const float*)(dsb + boc);       // global_load v,off,s[base]
        }
#pragma unroll
        for (int j = 0; j < 8; ++j) {
            unsigned u = eu[j];
            int x_i = (int)((u >> 14) & 255u);
            int y_i = (int)((u >> 22) & 255u);
            int dr = r - y_i, dc = cc - x_i;
            bool h = (u & (1u << 30)) && (((unsigned)dr <= 6u) & ((unsigned)dc <= 6u));
            float nim = fmaf(im, c, dv[j]) * __builtin_amdgcn_rcpf(c + 1.0f);
            im = h ? nim : im;          // image update reads pre-increment count
            int er = r - x_i, ec = cc - y_i;
            bool hc = (u >> 31) && (((unsigned)er <= 6u) & ((unsigned)ec <= 6u));
            c += hc ? 1.0f : 0.0f;      // counter at transposed slice (source bug)
        }
    }
    out[bc * (HH * WW) + r * WW + cc] = im;
}

extern "C" void kernel_launch(void* const* d_in, const int* in_sizes, int n_in,
                              void* d_out, int out_size, void* d_ws, size_t ws_size,
                              hipStream_t stream) {
    const float* img = (const float*)d_in[0];
    const float* Wp  = (const float*)d_in[1];
    const float* bp  = (const float*)d_in[2];
    const float* pe  = (const float*)d_in[3];
    const float* Wb  = (const float*)d_in[4];
    const float* bb  = (const float*)d_in[5];
    float* out = (float*)d_out;

    float* wsf = (float*)d_ws;
    float*    M   = wsf;                        // 2401 floats (pad to 2404)
    float*    K   = wsf + 2404;                 // 490  floats (pad to 492)
    unsigned* xy  = (unsigned*)(wsf + 2896);    // 414720 u32
    float*    pd  = wsf + 2896 + NTASK;         // 20,321,280 floats (den, direct)

    k_mk<<<12, 256, 0, stream>>>(Wp, bp, pe, Wb, bb, M, K);
    k_sim<<<BCN * PPOS / 4, 256, 0, stream>>>(img, M, K, xy, pd);
    k_apply<<<BCN * NTILE / 4, 256, 0, stream>>>(img, xy, pd, out);
}

// Round 19
// 297.069 us; speedup vs baseline: 1.3995x; 1.3995x over previous
//
#include <hip/hip_runtime.h>

#define PS 7
#define NP 10
#define WIN 20
#define STR 4
#define LL 14          // WIN - PS + 1
#define HALF 7
#define HH 160
#define WW 160
#define BCN 32         // B*C
#define NX 36          // positions per axis
#define PPOS 1296      // NX*NX
#define EMBD 128
#define NTASK (BCN * PPOS * NP)   // 414720
#define NEV (PPOS * NP)           // 12960 events per plane
#define CAP 512                   // per-tile event list capacity (8x8 tiles)
#define NTILE 400                 // 20x20 tiles of 8x8 per plane

// ---------------- phase 0: M = Wp@Wb, K[n] = (bp+pos_emb[n])@Wb + bb ---------
__global__ __launch_bounds__(256) void k_mk(const float* __restrict__ Wp,
                                            const float* __restrict__ bp,
                                            const float* __restrict__ pe,
                                            const float* __restrict__ Wb,
                                            const float* __restrict__ bb,
                                            float* __restrict__ M,
                                            float* __restrict__ K) {
    int t = blockIdx.x * 256 + threadIdx.x;
    if (t < 49 * 49) {
        int k = t / 49, d = t % 49;
        float acc = 0.f;
        for (int e = 0; e < EMBD; ++e) acc += Wp[k * EMBD + e] * Wb[e * 49 + d];
        M[t] = acc;
    } else if (t < 49 * 49 + NP * 49) {
        int u = t - 49 * 49;
        int n = u / 49, d = u % 49;
        float acc = bb[d];
        for (int e = 0; e < EMBD; ++e) acc += (bp[e] + pe[n * EMBD + e]) * Wb[e * 49 + d];
        K[u] = acc;
    }
}

// ---------------- phase 1: sim + top-10 + FUSED den (round-16 proven body) ---
// 4 independent waves per block (no LDS, no barriers). CRITICAL (round-18
// lesson): wv must go through readfirstlane so pos/x/y/plane stay in SGPRs —
// deriving them from tid>>6 directly made the whole body compiler-divergent
// (SGPR 80->32, the 490 s_load taps became vector loads, 2x regression).
__global__ __launch_bounds__(256) void k_sim(const float* __restrict__ img,
                                             const float* __restrict__ Mg,
                                             const float* __restrict__ Kg,
                                             unsigned* __restrict__ xy,
                                             float* __restrict__ pd) {
    int tid  = threadIdx.x;
    int wv   = __builtin_amdgcn_readfirstlane(tid >> 6);   // SGPR wave id
    int lane = tid & 63;
    int gt   = blockIdx.x * 4 + wv;    // SALU
    int pos  = gt % PPOS;
    int bc   = gt / PPOS;
    int ix = pos / NX, iy = pos % NX;
    int x = ix * STR, y = iy * STR;
    int xb0 = max(x - HALF, 0), yb0 = max(y - HALF, 0);
    int jmax = x + 6 - xb0;   // valid j <= jmax
    int imax = y + 6 - yb0;   // <= 13 always
    const float* plane = img + bc * (HH * WW);   // SGPR base

    // ref patch 7x7, wave-uniform -> s_loads
    float rf[49];
#pragma unroll
    for (int a = 0; a < PS; ++a)
#pragma unroll
        for (int b = 0; b < PS; ++b)
            rf[a * 7 + b] = plane[(y + a) * WW + (x + b)];

    int B = lane;                      // quad block id, valid < 56
    bool bval = B < 56;
    int gr = B / 14, c = B % 14;       // row-group, col
    int r0 = gr * 4;
    float acc[4] = {0.f, 0.f, 0.f, 0.f};
    const float* wb = plane + yb0 * WW + xb0 + c;
#pragma unroll
    for (int a = 0; a < 10; ++a) {
        int ra = min(r0 + a, 19);      // clamp keeps loads in-window
        const float* rp = wb + ra * WW;
#pragma unroll
        for (int b = 0; b < 7; ++b) {
            float tap = rp[b];
#pragma unroll
            for (int k = 0; k < 4; ++k) {
                int ai = a - k;
                if (ai >= 0 && ai < 7) acc[k] += tap * rf[ai * 7 + b];
            }
        }
    }
    float v[4]; int vidx[4];
#pragma unroll
    for (int k = 0; k < 4; ++k) {
        int rr = r0 + k;
        bool ok = bval && (rr <= imax) && (c <= jmax);  // imax<=13 masks rows 14/15
        v[k] = ok ? acc[k] : -INFINITY;
        vidx[k] = rr * 14 + c;         // monotone in lane per slot
    }

    // M column d cached per lane (rf[] live range ends above -> regs reused)
    int ld = min(lane, 48);
    float Mc[49];
#pragma unroll
    for (int j = 0; j < 49; ++j) Mc[j] = Mg[j * 49 + ld];  // coalesced, L1-hot

    bool act = lane < 49;
    int tbase = (bc * PPOS + pos) * NP;

    for (int n = 0; n < NP; ++n) {
        float bv = fmaxf(fmaxf(v[0], v[1]), fmaxf(v[2], v[3]));
#pragma unroll
        for (int off = 32; off >= 1; off >>= 1)
            bv = fmaxf(bv, __shfl_xor(bv, off));
        unsigned long long ms[4];
        ms[0] = __ballot(v[0] == bv);
        ms[1] = __ballot(v[1] == bv);
        ms[2] = __ballot(v[2] == bv);
        ms[3] = __ballot(v[3] == bv);
        int best = 1 << 30, slotw = 0, lanew = 0;
#pragma unroll
        for (int s = 0; s < 4; ++s) {
            if (ms[s]) {
                int l  = __ffsll(ms[s]) - 1;                       // SGPR
                int id = __builtin_amdgcn_readlane(vidx[s], l);    // SGPR
                if (id < best) { best = id; slotw = s; lanew = l; }
            }
        }
        int bi = best;                       // SGPR raster idx (unique)
#pragma unroll
        for (int s = 0; s < 4; ++s)
            if (s == slotw && lane == lanew) v[s] = -INFINITY;

        int oy = bi / 14, ox = bi % 14;      // SALU
        int x_i = oy + xb0;        // source bug kept: col start = row off + xb0
        int y_i = ox + yb0;        // row start = col off + yb0
        int t = tbase + n;
        if (lane == 0) xy[t] = (unsigned)x_i | ((unsigned)y_i << 8);
        const float* src = plane + (yb0 + oy) * WW + (xb0 + ox);   // SGPR base
        // den[lane] = K[n][lane] + sum_j patch_j * Mc[j];
        // patch_j = src[(j%7)*WW + j/7]  (transposed patch, uniform -> s_load)
        float den = Kg[n * 49 + ld];
#pragma unroll
        for (int j = 0; j < 49; ++j)
            den = fmaf(src[(j % 7) * WW + (j / 7)], Mc[j], den);
        if (act) pd[(size_t)t * 49 + lane] = den;
    }
}

// ---------------- phase 3: build (LDS u32 list) + replay (round-14 proven) ---
__global__ __launch_bounds__(256) void k_apply(const float* __restrict__ img,
                                               const unsigned* __restrict__ xy,
                                               const float* __restrict__ pd,
                                               float* __restrict__ out) {
    __shared__ unsigned lsts[4][CAP];
    int tid  = threadIdx.x;
    int wv   = tid >> 6;
    int lane = tid & 63;
    int gt   = blockIdx.x * 4 + wv;          // global tile id
    int bc   = gt / NTILE;
    int tile = gt % NTILE;
    int tx0 = (tile % 20) * 8, ty0 = (tile / 20) * 8;
    int tx1 = tx0 + 7, ty1 = ty0 + 7;
    const unsigned* xs = xy + bc * NEV;
    unsigned* lst = lsts[wv];

    // ---- build: interval-restricted scan ----
    int a0 = (tx0 <= 19) ? 0 : ((tx0 - 9) >> 2), a1 = min(35, (tx0 + 14) >> 2);
    int b0 = (ty0 <= 19) ? 0 : ((ty0 - 9) >> 2), b1 = min(35, (ty0 + 14) >> 2);
    if (a0 > b0) { int t0 = a0; a0 = b0; b0 = t0; int t1 = a1; a1 = b1; b1 = t1; }
    int lo0 = a0, lo1 = 0, len0, len1;
    if (b0 <= a1 + 1) { len0 = max(a1, b1) - lo0 + 1; len1 = 0; }
    else              { len0 = a1 - a0 + 1; lo1 = b0; len1 = b1 - b0 + 1; }
    int nU = len0 + len1;                    // <= 14
    unsigned m = 65536u / (unsigned)nU + 1u; // exact fastdiv (k < 4681, nU <= 14)
    int npos = nU * nU;

    unsigned cnt = 0;
    for (int base = 0; base < npos; base += 64) {
        int k = base + lane;
        bool valid = k < npos;
        unsigned kk = valid ? (unsigned)k : 0u;
        int ki = (int)((kk * m) >> 16);
        int kj = (int)kk - ki * nU;
        int ixp = (ki < len0) ? (lo0 + ki) : (lo1 + ki - len0);
        int iyp = (kj < len0) ? (lo0 + kj) : (lo1 + kj - len0);
        int pos = ixp * NX + iyp;
        const unsigned* ep = xs + pos * NP;

        unsigned ev[NP];
#pragma unroll
        for (int n = 0; n < NP; ++n) ev[n] = ep[n];

        unsigned rel = 0;
        unsigned pk[NP];
#pragma unroll
        for (int n = 0; n < NP; ++n) {
            unsigned u = ev[n];
            int x_i = (int)(u & 255u);
            int y_i = (int)((u >> 8) & 255u);
            bool ih = (x_i <= tx1) && (x_i + 6 >= tx0) &&
                      (y_i <= ty1) && (y_i + 6 >= ty0);
            bool ch = (x_i <= ty1) && (x_i + 6 >= ty0) &&
                      (y_i <= tx1) && (y_i + 6 >= tx0);
            bool any = valid && (ih || ch);
            rel |= any ? (1u << n) : 0u;
            pk[n] = (unsigned)(pos * NP + n) | ((unsigned)x_i << 14) | ((unsigned)y_i << 22)
                  | (ih ? (1u << 30) : 0u) | (ch ? (1u << 31) : 0u);
        }
        int myc = __popc(rel);
        int scan = myc;
#pragma unroll
        for (int off = 1; off < 64; off <<= 1) {
            int o = __shfl_up(scan, off);
            scan += (lane >= off) ? o : 0;
        }
        int excl  = (int)cnt + scan - myc;
        int total = __shfl(scan, 63);
        int w = excl;
#pragma unroll
        for (int n = 0; n < NP; ++n) {
            if ((rel >> n) & 1u) { if (w < CAP) lst[w] = pk[n]; ++w; }
        }
        cnt += (unsigned)total;
    }
    if (cnt > CAP) cnt = CAP;
    unsigned cntp = (cnt + 7u) & ~7u;
    if (cntp > CAP) cntp = CAP;
    if (lane < (int)(cntp - cnt)) lst[cnt + lane] = 0u;   // zero-pad (no-op)
    int cntN = (int)cntp;

    // ---- apply: batch-of-8, scalarized decode, pure predication ----
    int r  = ty0 + (lane >> 3);
    int cc = tx0 + (lane & 7);
    float im = img[bc * (HH * WW) + r * WW + cc];
    float c  = 1.0f;
    const float* ds = pd + (size_t)bc * ((size_t)NEV * 49);
    int vOff = (r * 7 + cc) * 4;   // per-lane byte offset base 4*(7r+cc)

    for (int i = 0; i < cntN; i += 8) {
        unsigned eu[8];
        float    dv[8];
#pragma unroll
        for (int j = 0; j < 8; ++j)
            eu[j] = (unsigned)__builtin_amdgcn_readfirstlane((int)lst[i + j]);
#pragma unroll
        for (int j = 0; j < 8; ++j) {
            unsigned u = eu[j];                       // SGPR
            int t    = (int)(u & 16383u);             // SALU decode
            int x_i  = (int)((u >> 14) & 255u);
            int y_i  = (int)((u >> 22) & 255u);
            int sOff = (y_i * 7 + x_i) * 4;           // SALU
            const char* dsb = (const char*)(ds + (size_t)t * 49);  // SGPR base
            int boc = min(max(vOff - sOff, 0), 192);  // v_sub + clamp
            dv[j] = *(const float*)(dsb + boc);       // global_load v,off,s[base]
        }
#pragma unroll
        for (int j = 0; j < 8; ++j) {
            unsigned u = eu[j];
            int x_i = (int)((u >> 14) & 255u);
            int y_i = (int)((u >> 22) & 255u);
            int dr = r - y_i, dc = cc - x_i;
            bool h = (u & (1u << 30)) && (((unsigned)dr <= 6u) & ((unsigned)dc <= 6u));
            float nim = fmaf(im, c, dv[j]) * __builtin_amdgcn_rcpf(c + 1.0f);
            im = h ? nim : im;          // image update reads pre-increment count
            int er = r - x_i, ec = cc - y_i;
            bool hc = (u >> 31) && (((unsigned)er <= 6u) & ((unsigned)ec <= 6u));
            c += hc ? 1.0f : 0.0f;      // counter at transposed slice (source bug)
        }
    }
    out[bc * (HH * WW) + r * WW + cc] = im;
}

extern "C" void kernel_launch(void* const* d_in, const int* in_sizes, int n_in,
                              void* d_out, int out_size, void* d_ws, size_t ws_size,
                              hipStream_t stream) {
    const float* img = (const float*)d_in[0];
    const float* Wp  = (const float*)d_in[1];
    const float* bp  = (const float*)d_in[2];
    const float* pe  = (const float*)d_in[3];
    const float* Wb  = (const float*)d_in[4];
    const float* bb  = (const float*)d_in[5];
    float* out = (float*)d_out;

    float* wsf = (float*)d_ws;
    float*    M   = wsf;                        // 2401 floats (pad to 2404)
    float*    K   = wsf + 2404;                 // 490  floats (pad to 492)
    unsigned* xy  = (unsigned*)(wsf + 2896);    // 414720 u32
    float*    pd  = wsf + 2896 + NTASK;         // 20,321,280 floats (den, direct)

    k_mk<<<12, 256, 0, stream>>>(Wp, bp, pe, Wb, bb, M, K);
    k_sim<<<BCN * PPOS / 4, 256, 0, stream>>>(img, M, K, xy, pd);
    k_apply<<<BCN * NTILE / 4, 256, 0, stream>>>(img, xy, pd, out);
}